// Round 1
// baseline (418.900 us; speedup 1.0000x reference)
//
#include <hip/hip_runtime.h>

typedef unsigned long long u64;

#define BB   32
#define CC   256
#define HH   56
#define WW   56
#define HWP  3136      // H*W
#define NPOS 100352    // B*H*W

// ---- workspace layout (bytes) ----
#define A_OFF    0ull
#define A_BYTES  (4ull * NPOS * 8ull)            // packed activations, word-major A[j*NPOS+pos]
#define WB_OFF   (A_OFF + A_BYTES)               // u64[3*256*4] packed weight signs
#define WB_BYTES (3ull * 256 * 4 * 8)
#define SC_OFF   (WB_OFF + WB_BYTES)             // float[3*256] weight scales
#define SC_BYTES (3ull * 256 * 4)
#define ST_OFF   (SC_OFF + SC_BYTES)             // double[512]: sum_s, sum_s2
#define ST_BYTES (512ull * 8)
#define PAR_OFF  (ST_OFF + ST_BYTES)             // float[512]: mul, add

// K0: pack weight sign bits + per-out-channel scale; zero stat accumulators.
__global__ __launch_bounds__(64) void k_pack_w(
    const float* __restrict__ w1, const float* __restrict__ w2,
    const float* __restrict__ w3, u64* __restrict__ wbits,
    float* __restrict__ scales, double* __restrict__ stats) {
  int bid = blockIdx.x;
  int conv = bid >> 8, p = bid & 255;
  const float* w = (conv == 0) ? w1 : (conv == 1) ? w2 : w3;
  int lane = threadIdx.x;
  float asum = 0.0f;
#pragma unroll
  for (int k = 0; k < 4; ++k) {
    float v = w[p * 256 + k * 64 + lane];
    asum += fabsf(v);
    u64 bal = __ballot(v > 0.0f);          // bit l <-> channel k*64+l
    if (lane == 0) wbits[(conv * 256 + p) * 4 + k] = bal;
  }
#pragma unroll
  for (int off = 32; off > 0; off >>= 1) asum += __shfl_down(asum, off);
  if (lane == 0) scales[conv * 256 + p] = asum * (1.0f / 256.0f);
  if (bid == 0) {
    for (int i = lane; i < 512; i += 64) stats[i] = 0.0;
  }
}

// K1: pack a = sign(x + bias0) into 4 u64 words per position (word-major).
// Each thread handles 2 adjacent positions -> float2 loads, ulonglong2 stores.
__global__ __launch_bounds__(256) void k_pack_a(
    const float* __restrict__ x, const float* __restrict__ bias0,
    u64* __restrict__ A) {
  int t = blockIdx.x * 256 + threadIdx.x;
  int pos = t * 2;
  int b = pos / HWP;
  int hw = pos - b * HWP;                 // even, so pos/pos+1 share image
  const float* xp = x + (size_t)b * CC * HWP + hw;
#pragma unroll
  for (int j = 0; j < 4; ++j) {
    u64 wlo = 0, whi = 0;
#pragma unroll
    for (int c = 0; c < 64; ++c) {
      float2 v = *(const float2*)(xp + (size_t)(j * 64 + c) * HWP);
      float bo = bias0[j * 64 + c];
      wlo |= (u64)((v.x + bo) > 0.0f) << c;
      whi |= (u64)((v.y + bo) > 0.0f) << c;
    }
    ulonglong2 ww; ww.x = wlo; ww.y = whi;
    *(ulonglong2*)(A + (size_t)j * NPOS + pos) = ww;
  }
}

__device__ __forceinline__ void shift_idx(int h, int w, int& hm1, int& hp1,
                                          int& wm1, int& wp1, int& hm3,
                                          int& hp3, int& wm3, int& wp3) {
  hm1 = (h == 0) ? 55 : h - 1;
  hp1 = (h == 55) ? 0 : h + 1;
  wm1 = (w == 0) ? 55 : w - 1;
  wp1 = (w == 55) ? 0 : w + 1;
  hm3 = (h < 3) ? h + 53 : h - 3;
  hp3 = (h >= 53) ? h - 53 : h + 3;
  wm3 = (w < 3) ? w + 53 : w - 3;
  wp3 = (w >= 53) ? w - 53 : w + 3;
}

// K2: per-channel BN statistics. thread = out-channel p; block walks 128
// positions with block-uniform A addresses (scalarizable). Accumulate
// sum(s), sum(s^2) and atomically add to stats.
__global__ __launch_bounds__(256) void k_stats(
    const u64* __restrict__ A, const u64* __restrict__ wbits,
    const float* __restrict__ scales, double* __restrict__ stats) {
  int p = threadIdx.x;
  u64 wb0[4], wb1[4], wb2[4];
#pragma unroll
  for (int j = 0; j < 4; ++j) {
    wb0[j] = wbits[p * 4 + j];
    wb1[j] = wbits[1024 + p * 4 + j];
    wb2[j] = wbits[2048 + p * 4 + j];
  }
  float sc0 = scales[p], sc1 = scales[256 + p], sc2 = scales[512 + p];
  float acc = 0.0f, acc2 = 0.0f;
  int pos0 = blockIdx.x * 128;
  for (int i = 0; i < 128; ++i) {
    int pos = pos0 + i;
    int b = pos / HWP;
    int hw = pos - b * HWP;
    int h = hw / WW;
    int w = hw - h * WW;
    int ib = b * HWP;
    int hm1, hp1, wm1, wp1, hm3, hp3, wm3, wp3;
    shift_idx(h, w, hm1, hp1, wm1, wp1, hm3, hp3, wm3, wp3);
    u64 a0 = A[pos], a1 = A[NPOS + pos], a2 = A[2 * NPOS + pos],
        a3 = A[3 * NPOS + pos];
    u64 s0 = A[ib + hm1 * WW + w];
    u64 s1 = A[NPOS + ib + hp1 * WW + w];
    u64 s2 = A[2 * NPOS + ib + h * WW + wm1];
    u64 s3 = A[3 * NPOS + ib + h * WW + wp1];
    u64 g0 = A[ib + hm3 * WW + w];
    u64 g1 = A[NPOS + ib + hp3 * WW + w];
    u64 g2 = A[2 * NPOS + ib + h * WW + wm3];
    u64 g3 = A[3 * NPOS + ib + h * WW + wp3];
    int pc0 = __popcll(a0 ^ wb0[0]) + __popcll(a1 ^ wb0[1]) +
              __popcll(a2 ^ wb0[2]) + __popcll(a3 ^ wb0[3]);
    int pc1 = __popcll(s0 ^ wb1[0]) + __popcll(s1 ^ wb1[1]) +
              __popcll(s2 ^ wb1[2]) + __popcll(s3 ^ wb1[3]);
    int pc2 = __popcll(g0 ^ wb2[0]) + __popcll(g1 ^ wb2[1]) +
              __popcll(g2 ^ wb2[2]) + __popcll(g3 ^ wb2[3]);
    float s = (float)(256 - 2 * pc0) * sc0;
    s = fmaf((float)(256 - 2 * pc1), sc1, s);
    s = fmaf((float)(256 - 2 * pc2), sc2, s);
    acc += s;
    acc2 = fmaf(s, s, acc2);
  }
  atomicAdd(&stats[p], (double)acc);
  atomicAdd(&stats[256 + p], (double)acc2);
}

// K3: finalize BN -> per-channel affine (folds gamma, beta, bias1, mean, var).
__global__ __launch_bounds__(256) void k_bn(
    const double* __restrict__ stats, const float* __restrict__ gamma,
    const float* __restrict__ beta, const float* __restrict__ bias1,
    float* __restrict__ par) {
  int p = threadIdx.x;
  double mean = stats[p] * (1.0 / NPOS);
  double var = stats[256 + p] * (1.0 / NPOS) - mean * mean;
  float m = (float)((double)gamma[p] / sqrt(var + 1e-5));
  par[p] = m;
  par[256 + p] = beta[p] + bias1[p] - (float)mean * m;
}

// K4: recompute dots, apply BN + residual + PReLU + bias2, write out.
// thread = position (coalesced x/out); weights+params broadcast from LDS.
__global__ __launch_bounds__(256) void k_out(
    const u64* __restrict__ A, const u64* __restrict__ wbits,
    const float* __restrict__ scales, const float* __restrict__ par,
    const float* __restrict__ alpha, const float* __restrict__ bias2,
    const float* __restrict__ x, float* __restrict__ out) {
  __shared__ u64 swb[3072];
  __shared__ float sp[1792];  // 0:mul 256:add 512:alpha 768:bias2 1024:scales(3*256)
  int tid = threadIdx.x;
#pragma unroll
  for (int i = 0; i < 12; ++i) swb[tid + 256 * i] = wbits[tid + 256 * i];
  sp[tid] = par[tid];
  sp[256 + tid] = par[256 + tid];
  sp[512 + tid] = alpha[tid];
  sp[768 + tid] = bias2[tid];
#pragma unroll
  for (int i = 0; i < 3; ++i) sp[1024 + 256 * i + tid] = scales[256 * i + tid];
  __syncthreads();

  int pos = blockIdx.x * 256 + tid;
  int b = pos / HWP;
  int hw = pos - b * HWP;
  int h = hw / WW;
  int w = hw - h * WW;
  int ib = b * HWP;
  int hm1, hp1, wm1, wp1, hm3, hp3, wm3, wp3;
  shift_idx(h, w, hm1, hp1, wm1, wp1, hm3, hp3, wm3, wp3);
  u64 a0 = A[pos], a1 = A[NPOS + pos], a2 = A[2 * NPOS + pos],
      a3 = A[3 * NPOS + pos];
  u64 s0 = A[ib + hm1 * WW + w];
  u64 s1 = A[NPOS + ib + hp1 * WW + w];
  u64 s2 = A[2 * NPOS + ib + h * WW + wm1];
  u64 s3 = A[3 * NPOS + ib + h * WW + wp1];
  u64 g0 = A[ib + hm3 * WW + w];
  u64 g1 = A[NPOS + ib + hp3 * WW + w];
  u64 g2 = A[2 * NPOS + ib + h * WW + wm3];
  u64 g3 = A[3 * NPOS + ib + h * WW + wp3];

  const float* xp = x + (size_t)b * CC * HWP + hw;
  float* op = out + (size_t)b * CC * HWP + hw;
#pragma unroll 4
  for (int p = 0; p < 256; ++p) {
    int pc0 = __popcll(a0 ^ swb[p * 4 + 0]) + __popcll(a1 ^ swb[p * 4 + 1]) +
              __popcll(a2 ^ swb[p * 4 + 2]) + __popcll(a3 ^ swb[p * 4 + 3]);
    int pc1 = __popcll(s0 ^ swb[1024 + p * 4 + 0]) +
              __popcll(s1 ^ swb[1024 + p * 4 + 1]) +
              __popcll(s2 ^ swb[1024 + p * 4 + 2]) +
              __popcll(s3 ^ swb[1024 + p * 4 + 3]);
    int pc2 = __popcll(g0 ^ swb[2048 + p * 4 + 0]) +
              __popcll(g1 ^ swb[2048 + p * 4 + 1]) +
              __popcll(g2 ^ swb[2048 + p * 4 + 2]) +
              __popcll(g3 ^ swb[2048 + p * 4 + 3]);
    float s = (float)(256 - 2 * pc0) * sp[1024 + p];
    s = fmaf((float)(256 - 2 * pc1), sp[1280 + p], s);
    s = fmaf((float)(256 - 2 * pc2), sp[1536 + p], s);
    float t = fmaf(s, sp[p], sp[256 + p]) + xp[(size_t)p * HWP];
    float o = (t >= 0.0f) ? t : sp[512 + p] * t;
    op[(size_t)p * HWP] = o + sp[768 + p];
  }
}

extern "C" void kernel_launch(void* const* d_in, const int* in_sizes, int n_in,
                              void* d_out, int out_size, void* d_ws,
                              size_t ws_size, hipStream_t stream) {
  const float* x     = (const float*)d_in[0];
  const float* bias0 = (const float*)d_in[1];
  const float* w1    = (const float*)d_in[2];
  const float* w2    = (const float*)d_in[3];
  const float* w3    = (const float*)d_in[4];
  const float* gamma = (const float*)d_in[5];
  const float* beta  = (const float*)d_in[6];
  const float* bias1 = (const float*)d_in[7];
  const float* alpha = (const float*)d_in[8];
  const float* bias2 = (const float*)d_in[9];
  float* out = (float*)d_out;

  char* ws = (char*)d_ws;
  u64* A        = (u64*)(ws + A_OFF);
  u64* wbits    = (u64*)(ws + WB_OFF);
  float* scales = (float*)(ws + SC_OFF);
  double* stats = (double*)(ws + ST_OFF);
  float* par    = (float*)(ws + PAR_OFF);

  hipLaunchKernelGGL(k_pack_w, dim3(768), dim3(64), 0, stream, w1, w2, w3,
                     wbits, scales, stats);
  hipLaunchKernelGGL(k_pack_a, dim3(196), dim3(256), 0, stream, x, bias0, A);
  hipLaunchKernelGGL(k_stats, dim3(784), dim3(256), 0, stream, A, wbits,
                     scales, stats);
  hipLaunchKernelGGL(k_bn, dim3(1), dim3(256), 0, stream, stats, gamma, beta,
                     bias1, par);
  hipLaunchKernelGGL(k_out, dim3(392), dim3(256), 0, stream, A, wbits, scales,
                     par, alpha, bias2, x, out);
}

// Round 3
// 370.056 us; speedup vs baseline: 1.1320x; 1.1320x over previous
//
#include <hip/hip_runtime.h>

typedef unsigned int u32;
typedef int i32x4 __attribute__((ext_vector_type(4)));
typedef float f32x4 __attribute__((ext_vector_type(4)));

#define HWP  3136      // H*W
#define NPOS 100352    // B*H*W
#define NMBLK 1568     // NPOS / 64  (M-blocks; 49 per image)

// ---- workspace layout (bytes) ----
#define ACT_OFF 0ull
#define ACT_BYTES (25690112ull)                 // i8 act [NPOS][256]
#define W8_OFF  (ACT_OFF + ACT_BYTES)           // i8 w   [3][256][256]
#define W8_BYTES (196608ull)
#define SC_OFF  (W8_OFF + W8_BYTES)             // f32 scales [3][256]
#define SC_BYTES (3072ull)
#define PS_OFF  (SC_OFF + SC_BYTES)             // f32 ps [256][NMBLK]
#define PS_BYTES (256ull * NMBLK * 4)
#define PQ_OFF  (PS_OFF + PS_BYTES)             // f32 pq [256][NMBLK]
#define PQ_BYTES (256ull * NMBLK * 4)
#define PAR_OFF (PQ_OFF + PQ_BYTES)             // f32 par [2][256]

// K0: weights -> i8 sign (+1/-1), per-out-channel scale = mean|w|.
__global__ __launch_bounds__(64) void k_pack_w(
    const float* __restrict__ w1, const float* __restrict__ w2,
    const float* __restrict__ w3, signed char* __restrict__ w8,
    float* __restrict__ scales) {
  int bid = blockIdx.x;
  int conv = bid >> 8, p = bid & 255;
  const float* w = (conv == 0) ? w1 : (conv == 1) ? w2 : w3;
  int lane = threadIdx.x;
  float asum = 0.0f;
#pragma unroll
  for (int k = 0; k < 4; ++k) {
    float v = w[p * 256 + k * 64 + lane];
    asum += fabsf(v);
    w8[(size_t)(conv * 256 + p) * 256 + k * 64 + lane] =
        (v > 0.0f) ? (signed char)1 : (signed char)-1;
  }
#pragma unroll
  for (int off = 32; off > 0; off >>= 1) asum += __shfl_down(asum, off);
  if (lane == 0) scales[conv * 256 + p] = asum * (1.0f / 256.0f);
}

// K1: act[pos][c] = sign(x + bias0) as i8 (+1 -> 0x01, -1 -> 0xFF).
// thread = 1 position; packs 16 channels into an i32x4 -> 16B stores
// (4x fewer VMEM transactions than u32 stores).
__global__ __launch_bounds__(256) void k_pack_a(
    const float* __restrict__ x, const float* __restrict__ bias0,
    i32x4* __restrict__ act16) {
  int pos = blockIdx.x * 256 + threadIdx.x;
  int b = pos / HWP;
  int hw = pos - b * HWP;
  const float* xp = x + (size_t)b * 256 * HWP + hw;
  i32x4* op = act16 + (size_t)pos * 16;
#pragma unroll 2
  for (int c16 = 0; c16 < 16; ++c16) {
    i32x4 vv;
#pragma unroll
    for (int q = 0; q < 4; ++q) {
      u32 bb = 0;
#pragma unroll
      for (int cc = 0; cc < 4; ++cc) {
        int c = c16 * 16 + q * 4 + cc;
        float v = xp[(size_t)c * HWP] + bias0[c];
        bb |= (u32)((v > 0.0f) ? 0x01u : 0xFFu) << (cc * 8);
      }
      vv[q] = (int)bb;
    }
    op[c16] = vv;
  }
}

// Shared GEMM core: block = (m, n0); 512 threads = 8 waves; each wave owns 16
// output channels (n0 + wid*16 .. +15) and all 64 positions (4 msub tiles).
// Stages 3 shift-variant A tiles [64 pos][256 ch] i8 in LDS (XOR-swizzled
// 16B chunks), holds B fragments (3 convs x 4 ksteps) in VGPRs, runs
// mfma_i32_16x16x64_i8, combines the three integer dots with scales -> f32 s.
// D layout (HW-verified): col = lane&15 (channel), row = (lane>>4)*4 + reg.
// A layout (derived): lane holds row=lane&15, k=(lane>>4)*16+j.
// B layout (derived): lane holds col=lane&15, k=(lane>>4)*16+j -> w8[ch][k].
__device__ __forceinline__ void compute_s(
    int m, int n0, const signed char* __restrict__ act,
    const signed char* __restrict__ w8, const float* __restrict__ scales,
    signed char* lds, f32x4 (&sout)[4]) {
  const int tid = threadIdx.x;
  const int lane = tid & 63, wid = tid >> 6;
  const int l15 = lane & 15, l4 = lane >> 4;
  const int ch = n0 + wid * 16 + l15;

  // B fragments: B[k][col=ch], k = ks*64 + l4*16 + j  -> w8[conv][ch][k]
  i32x4 bfrag[3][4];
#pragma unroll
  for (int conv = 0; conv < 3; ++conv)
#pragma unroll
    for (int ks = 0; ks < 4; ++ks)
      bfrag[conv][ks] = *(const i32x4*)(w8 + (size_t)(conv * 256 + ch) * 256 +
                                        ks * 64 + l4 * 16);
  float sc0 = scales[ch], sc1 = scales[256 + ch], sc2 = scales[512 + ch];

  // Stage A tiles (3 x 64 rows x 256B), 16B chunks, XOR swizzle on chunk idx.
  int bimg = m / 49;
  int hw0 = (m - bimg * 49) * 64;
  for (int id = tid; id < 3072; id += 512) {
    int tile = id >> 10;
    int rem = id & 1023;
    int row = rem >> 4;
    int c16 = rem & 15;
    int grp = c16 >> 2;  // channel group 0..3 (64 ch each)
    int hw = hw0 + row;
    int h = hw / 56, w = hw - h * 56;
    int sh = h, sw = w;
    if (tile == 1) {
      if (grp == 0)      sh = (h == 0) ? 55 : h - 1;
      else if (grp == 1) sh = (h == 55) ? 0 : h + 1;
      else if (grp == 2) sw = (w == 0) ? 55 : w - 1;
      else               sw = (w == 55) ? 0 : w + 1;
    } else if (tile == 2) {
      if (grp == 0)      sh = (h < 3) ? h + 53 : h - 3;
      else if (grp == 1) sh = (h >= 53) ? h - 53 : h + 3;
      else if (grp == 2) sw = (w < 3) ? w + 53 : w - 3;
      else               sw = (w >= 53) ? w - 53 : w + 3;
    }
    size_t spos = (size_t)(bimg * HWP + sh * 56 + sw);
    i32x4 v = *(const i32x4*)(act + spos * 256 + c16 * 16);
    *(i32x4*)(lds + tile * 16384 + row * 256 + ((c16 ^ (row & 7)) << 4)) = v;
  }
  __syncthreads();

#pragma unroll
  for (int msub = 0; msub < 4; ++msub) {
    int row = msub * 16 + l15;
    int rx = row & 7;
    i32x4 acc0 = {0, 0, 0, 0}, acc1 = {0, 0, 0, 0}, acc2 = {0, 0, 0, 0};
#pragma unroll
    for (int ks = 0; ks < 4; ++ks) {
      int off = row * 256 + (((ks * 4 + l4) ^ rx) << 4);
      i32x4 a0 = *(const i32x4*)(lds + off);
      i32x4 a1 = *(const i32x4*)(lds + 16384 + off);
      i32x4 a2 = *(const i32x4*)(lds + 32768 + off);
      acc0 = __builtin_amdgcn_mfma_i32_16x16x64_i8(a0, bfrag[0][ks], acc0, 0, 0, 0);
      acc1 = __builtin_amdgcn_mfma_i32_16x16x64_i8(a1, bfrag[1][ks], acc1, 0, 0, 0);
      acc2 = __builtin_amdgcn_mfma_i32_16x16x64_i8(a2, bfrag[2][ks], acc2, 0, 0, 0);
    }
    f32x4 s;
#pragma unroll
    for (int r = 0; r < 4; ++r)
      s[r] = sc0 * (float)acc0[r] + sc1 * (float)acc1[r] + sc2 * (float)acc2[r];
    sout[msub] = s;
  }
}

// K2: GEMM + BN-statistics partials (deterministic, no atomics).
__global__ __launch_bounds__(512) void k_stats2(
    const signed char* __restrict__ act, const signed char* __restrict__ w8,
    const float* __restrict__ scales, float* __restrict__ ps,
    float* __restrict__ pq) {
  __shared__ alignas(16) signed char lds[49152];
  int m = blockIdx.x, n0 = blockIdx.y * 128;
  f32x4 s[4];
  compute_s(m, n0, act, w8, scales, lds, s);
  float ss = 0.0f, sq = 0.0f;
#pragma unroll
  for (int msub = 0; msub < 4; ++msub)
#pragma unroll
    for (int r = 0; r < 4; ++r) {
      ss += s[msub][r];
      sq = fmaf(s[msub][r], s[msub][r], sq);
    }
  ss += __shfl_xor(ss, 16); sq += __shfl_xor(sq, 16);
  ss += __shfl_xor(ss, 32); sq += __shfl_xor(sq, 32);
  int lane = threadIdx.x & 63, wid = threadIdx.x >> 6;
  if ((lane >> 4) == 0) {
    int ch = n0 + wid * 16 + lane;
    ps[(size_t)ch * NMBLK + m] = ss;
    pq[(size_t)ch * NMBLK + m] = sq;
  }
}

// K3: reduce partials (f64) -> folded BN affine (gamma,beta,bias1,mean,var).
__global__ __launch_bounds__(256) void k_bn(
    const float* __restrict__ ps, const float* __restrict__ pq,
    const float* __restrict__ gamma, const float* __restrict__ beta,
    const float* __restrict__ bias1, float* __restrict__ par) {
  int ch = blockIdx.x;
  int tid = threadIdx.x;
  double as = 0.0, aq = 0.0;
  for (int i = tid; i < NMBLK; i += 256) {
    as += (double)ps[(size_t)ch * NMBLK + i];
    aq += (double)pq[(size_t)ch * NMBLK + i];
  }
  __shared__ double sd0[256], sd1[256];
  sd0[tid] = as; sd1[tid] = aq;
  __syncthreads();
  for (int s = 128; s > 0; s >>= 1) {
    if (tid < s) { sd0[tid] += sd0[tid + s]; sd1[tid] += sd1[tid + s]; }
    __syncthreads();
  }
  if (tid == 0) {
    double mean = sd0[0] * (1.0 / NPOS);
    double var = sd1[0] * (1.0 / NPOS) - mean * mean;
    float mm = (float)((double)gamma[ch] / sqrt(var + 1e-5));
    par[ch] = mm;
    par[256 + ch] = beta[ch] + bias1[ch] - (float)mean * mm;
  }
}

// K4: GEMM + BN affine + residual + PReLU + bias2 -> out (NCHW f32).
__global__ __launch_bounds__(512) void k_out2(
    const signed char* __restrict__ act, const signed char* __restrict__ w8,
    const float* __restrict__ scales, const float* __restrict__ par,
    const float* __restrict__ alpha, const float* __restrict__ bias2,
    const float* __restrict__ x, float* __restrict__ out) {
  __shared__ alignas(16) signed char lds[49152];
  int m = blockIdx.x, n0 = blockIdx.y * 128;
  f32x4 s[4];
  compute_s(m, n0, act, w8, scales, lds, s);
  int tid = threadIdx.x, lane = tid & 63, wid = tid >> 6;
  int l15 = lane & 15, l4 = lane >> 4;
  int ch = n0 + wid * 16 + l15;
  float mul = par[ch], add = par[256 + ch], al = alpha[ch], b2 = bias2[ch];
  int bimg = m / 49;
  int hw0 = (m - bimg * 49) * 64;
  size_t base = ((size_t)bimg * 256 + ch) * HWP + hw0 + l4 * 4;
#pragma unroll
  for (int msub = 0; msub < 4; ++msub) {
    f32x4 xv = *(const f32x4*)(x + base + msub * 16);
    f32x4 o;
#pragma unroll
    for (int r = 0; r < 4; ++r) {
      float t = fmaf(s[msub][r], mul, add) + xv[r];
      t = (t >= 0.0f) ? t : al * t;
      o[r] = t + b2;
    }
    *(f32x4*)(out + base + msub * 16) = o;
  }
}

extern "C" void kernel_launch(void* const* d_in, const int* in_sizes, int n_in,
                              void* d_out, int out_size, void* d_ws,
                              size_t ws_size, hipStream_t stream) {
  const float* x     = (const float*)d_in[0];
  const float* bias0 = (const float*)d_in[1];
  const float* w1    = (const float*)d_in[2];
  const float* w2    = (const float*)d_in[3];
  const float* w3    = (const float*)d_in[4];
  const float* gamma = (const float*)d_in[5];
  const float* beta  = (const float*)d_in[6];
  const float* bias1 = (const float*)d_in[7];
  const float* alpha = (const float*)d_in[8];
  const float* bias2 = (const float*)d_in[9];
  float* out = (float*)d_out;

  char* ws = (char*)d_ws;
  signed char* act = (signed char*)(ws + ACT_OFF);
  i32x4* act16     = (i32x4*)(ws + ACT_OFF);
  signed char* w8  = (signed char*)(ws + W8_OFF);
  float* scales    = (float*)(ws + SC_OFF);
  float* ps        = (float*)(ws + PS_OFF);
  float* pq        = (float*)(ws + PQ_OFF);
  float* par       = (float*)(ws + PAR_OFF);

  hipLaunchKernelGGL(k_pack_w, dim3(768), dim3(64), 0, stream, w1, w2, w3, w8,
                     scales);
  hipLaunchKernelGGL(k_pack_a, dim3(392), dim3(256), 0, stream, x, bias0,
                     act16);
  hipLaunchKernelGGL(k_stats2, dim3(NMBLK, 2), dim3(512), 0, stream, act, w8,
                     scales, ps, pq);
  hipLaunchKernelGGL(k_bn, dim3(256), dim3(256), 0, stream, ps, pq, gamma,
                     beta, bias1, par);
  hipLaunchKernelGGL(k_out2, dim3(NMBLK, 2), dim3(512), 0, stream, act, w8,
                     scales, par, alpha, bias2, x, out);
}

// Round 4
// 359.482 us; speedup vs baseline: 1.1653x; 1.0294x over previous
//
#include <hip/hip_runtime.h>

typedef unsigned int u32;
typedef int i32x4 __attribute__((ext_vector_type(4)));
typedef float f32x4 __attribute__((ext_vector_type(4)));

#define HWP  3136      // H*W
#define NPOS 100352    // B*H*W
#define NMBLK 1568     // NPOS / 64  (M-blocks; 49 per image)

// ---- workspace layout (bytes) ----
// act_t: chunk-major packed activations: act_t[chunk(0..15)][pos][16B]
#define ACT_OFF 0ull
#define ACT_BYTES (25690112ull)
#define W8_OFF  (ACT_OFF + ACT_BYTES)           // i8 w   [3][256][256]
#define W8_BYTES (196608ull)
#define SC_OFF  (W8_OFF + W8_BYTES)             // f32 scales [3][256]
#define SC_BYTES (3072ull)
#define PS_OFF  (SC_OFF + SC_BYTES)             // f32 ps [256][NMBLK]
#define PS_BYTES (256ull * NMBLK * 4)
#define PQ_OFF  (PS_OFF + PS_BYTES)             // f32 pq [256][NMBLK]
#define PQ_BYTES (256ull * NMBLK * 4)
#define PAR_OFF (PQ_OFF + PQ_BYTES)             // f32 par [2][256]

// K0: weights -> i8 sign (+1/-1), per-out-channel scale = mean|w|.
__global__ __launch_bounds__(64) void k_pack_w(
    const float* __restrict__ w1, const float* __restrict__ w2,
    const float* __restrict__ w3, signed char* __restrict__ w8,
    float* __restrict__ scales) {
  int bid = blockIdx.x;
  int conv = bid >> 8, p = bid & 255;
  const float* w = (conv == 0) ? w1 : (conv == 1) ? w2 : w3;
  int lane = threadIdx.x;
  float asum = 0.0f;
#pragma unroll
  for (int k = 0; k < 4; ++k) {
    float v = w[p * 256 + k * 64 + lane];
    asum += fabsf(v);
    w8[(size_t)(conv * 256 + p) * 256 + k * 64 + lane] =
        (v > 0.0f) ? (signed char)1 : (signed char)-1;
  }
#pragma unroll
  for (int off = 32; off > 0; off >>= 1) asum += __shfl_down(asum, off);
  if (lane == 0) scales[conv * 256 + p] = asum * (1.0f / 256.0f);
}

// K1: act_t[chunk][pos] = sign(x + bias0) as i8 (+1 -> 0x01, -1 -> 0xFF),
// chunk-major: 16B per (chunk,pos). Lanes = consecutive pos -> 1KB
// contiguous per store instruction.
__global__ __launch_bounds__(256) void k_pack_a(
    const float* __restrict__ x, const float* __restrict__ bias0,
    i32x4* __restrict__ act16) {
  int pos = blockIdx.x * 256 + threadIdx.x;
  int b = pos / HWP;
  int hw = pos - b * HWP;
  const float* xp = x + (size_t)b * 256 * HWP + hw;
#pragma unroll 2
  for (int c16 = 0; c16 < 16; ++c16) {
    i32x4 vv;
#pragma unroll
    for (int q = 0; q < 4; ++q) {
      u32 bb = 0;
#pragma unroll
      for (int cc = 0; cc < 4; ++cc) {
        int c = c16 * 16 + q * 4 + cc;
        float v = xp[(size_t)c * HWP] + bias0[c];
        bb |= (u32)((v > 0.0f) ? 0x01u : 0xFFu) << (cc * 8);
      }
      vv[q] = (int)bb;
    }
    act16[(size_t)c16 * NPOS + pos] = vv;
  }
}

// Neighbor positions for the 9 shift variants (circular roll per image).
// [0]=self; conv1: [1]=h-1 [2]=h+1 [3]=w-1 [4]=w+1; conv2: [5..8] same w/ 3.
__device__ __forceinline__ void neighbor_pos(int row, int base, int (&p9)[9]) {
  int h = row / 56;
  int w = row - h * 56;
  p9[0] = base + row;
  int hm1 = (h == 0) ? 55 : h - 1, hp1 = (h == 55) ? 0 : h + 1;
  int wm1 = (w == 0) ? 55 : w - 1, wp1 = (w == 55) ? 0 : w + 1;
  int hm3 = (h < 3) ? h + 53 : h - 3, hp3 = (h >= 53) ? h - 53 : h + 3;
  int wm3 = (w < 3) ? w + 53 : w - 3, wp3 = (w >= 53) ? w - 53 : w + 3;
  p9[1] = base + hm1 * 56 + w;  p9[2] = base + hp1 * 56 + w;
  p9[3] = base + h * 56 + wm1;  p9[4] = base + h * 56 + wp1;
  p9[5] = base + hm3 * 56 + w;  p9[6] = base + hp3 * 56 + w;
  p9[7] = base + h * 56 + wm3;  p9[8] = base + h * 56 + wp3;
}

// Shared GEMM core — NO LDS, NO barriers. Block = (m, n0); 512 thr = 8 waves;
// wave owns 16 channels x 64 positions (4 msub 16x16x64 MFMA tiles).
// A fragments loaded per-lane from chunk-major act_t (L2/L3-resident,
// 256B-contiguous runs). B fragments (3 convs x 4 ks) in VGPRs.
// Shift group g == k-slice ks, so each (conv,ks) has ONE uniform row offset.
// D layout (HW-verified): col = lane&15, row = (lane>>4)*4 + reg.
__device__ __forceinline__ void compute_s(
    int m, int n0, const i32x4* __restrict__ act16,
    const signed char* __restrict__ w8, const float* __restrict__ scales,
    f32x4 (&sout)[4]) {
  const int tid = threadIdx.x;
  const int lane = tid & 63, wid = tid >> 6;
  const int l15 = lane & 15, l4 = lane >> 4;
  const int ch = n0 + wid * 16 + l15;

  i32x4 bfrag[3][4];
#pragma unroll
  for (int conv = 0; conv < 3; ++conv)
#pragma unroll
    for (int ks = 0; ks < 4; ++ks)
      bfrag[conv][ks] = *(const i32x4*)(w8 + (size_t)(conv * 256 + ch) * 256 +
                                        ks * 64 + l4 * 16);
  float sc0 = scales[ch], sc1 = scales[256 + ch], sc2 = scales[512 + ch];

  int bimg = m / 49;
  int hw0 = (m - bimg * 49) * 64;
  int base = bimg * HWP;

#pragma unroll
  for (int msub = 0; msub < 4; ++msub) {
    int row = hw0 + msub * 16 + l15;
    int p9[9];
    neighbor_pos(row, base, p9);
    i32x4 acc0 = {0, 0, 0, 0}, acc1 = {0, 0, 0, 0}, acc2 = {0, 0, 0, 0};
    i32x4 a0[4], a1[4], a2[4];
#pragma unroll
    for (int ks = 0; ks < 4; ++ks) {
      const i32x4* cb = act16 + (size_t)(ks * 4 + l4) * NPOS;
      a0[ks] = cb[p9[0]];
      a1[ks] = cb[p9[1 + ks]];
      a2[ks] = cb[p9[5 + ks]];
    }
#pragma unroll
    for (int ks = 0; ks < 4; ++ks) {
      acc0 = __builtin_amdgcn_mfma_i32_16x16x64_i8(a0[ks], bfrag[0][ks], acc0, 0, 0, 0);
      acc1 = __builtin_amdgcn_mfma_i32_16x16x64_i8(a1[ks], bfrag[1][ks], acc1, 0, 0, 0);
      acc2 = __builtin_amdgcn_mfma_i32_16x16x64_i8(a2[ks], bfrag[2][ks], acc2, 0, 0, 0);
    }
    f32x4 s;
#pragma unroll
    for (int r = 0; r < 4; ++r)
      s[r] = sc0 * (float)acc0[r] + sc1 * (float)acc1[r] + sc2 * (float)acc2[r];
    sout[msub] = s;
  }
}

// Bijective XCD swizzle for m (1568 % 8 == 0): each XCD owns a contiguous
// run of 196 m-tiles -> shift-halo re-reads hit the home XCD's L2.
__device__ __forceinline__ int swz_m(int bid) {
  return (bid & 7) * 196 + (bid >> 3);
}

// K2: GEMM + BN-statistics partials (deterministic, no atomics).
__global__ __launch_bounds__(512) void k_stats2(
    const i32x4* __restrict__ act16, const signed char* __restrict__ w8,
    const float* __restrict__ scales, float* __restrict__ ps,
    float* __restrict__ pq) {
  int m = swz_m(blockIdx.x), n0 = blockIdx.y * 128;
  f32x4 s[4];
  compute_s(m, n0, act16, w8, scales, s);
  float ss = 0.0f, sq = 0.0f;
#pragma unroll
  for (int msub = 0; msub < 4; ++msub)
#pragma unroll
    for (int r = 0; r < 4; ++r) {
      ss += s[msub][r];
      sq = fmaf(s[msub][r], s[msub][r], sq);
    }
  ss += __shfl_xor(ss, 16); sq += __shfl_xor(sq, 16);
  ss += __shfl_xor(ss, 32); sq += __shfl_xor(sq, 32);
  int lane = threadIdx.x & 63, wid = threadIdx.x >> 6;
  if ((lane >> 4) == 0) {
    int ch = n0 + wid * 16 + lane;
    ps[(size_t)ch * NMBLK + m] = ss;
    pq[(size_t)ch * NMBLK + m] = sq;
  }
}

// K3: reduce partials (f64) -> folded BN affine (gamma,beta,bias1,mean,var).
__global__ __launch_bounds__(256) void k_bn(
    const float* __restrict__ ps, const float* __restrict__ pq,
    const float* __restrict__ gamma, const float* __restrict__ beta,
    const float* __restrict__ bias1, float* __restrict__ par) {
  int ch = blockIdx.x;
  int tid = threadIdx.x;
  double as = 0.0, aq = 0.0;
  for (int i = tid; i < NMBLK; i += 256) {
    as += (double)ps[(size_t)ch * NMBLK + i];
    aq += (double)pq[(size_t)ch * NMBLK + i];
  }
  __shared__ double sd0[256], sd1[256];
  sd0[tid] = as; sd1[tid] = aq;
  __syncthreads();
  for (int s = 128; s > 0; s >>= 1) {
    if (tid < s) { sd0[tid] += sd0[tid + s]; sd1[tid] += sd1[tid + s]; }
    __syncthreads();
  }
  if (tid == 0) {
    double mean = sd0[0] * (1.0 / NPOS);
    double var = sd1[0] * (1.0 / NPOS) - mean * mean;
    float mm = (float)((double)gamma[ch] / sqrt(var + 1e-5));
    par[ch] = mm;
    par[256 + ch] = beta[ch] + bias1[ch] - (float)mean * mm;
  }
}

// K4: GEMM + BN affine + residual + PReLU + bias2 -> out (NCHW f32).
__global__ __launch_bounds__(512) void k_out2(
    const i32x4* __restrict__ act16, const signed char* __restrict__ w8,
    const float* __restrict__ scales, const float* __restrict__ par,
    const float* __restrict__ alpha, const float* __restrict__ bias2,
    const float* __restrict__ x, float* __restrict__ out) {
  int m = swz_m(blockIdx.x), n0 = blockIdx.y * 128;
  f32x4 s[4];
  compute_s(m, n0, act16, w8, scales, s);
  int tid = threadIdx.x, lane = tid & 63, wid = tid >> 6;
  int l15 = lane & 15, l4 = lane >> 4;
  int ch = n0 + wid * 16 + l15;
  float mul = par[ch], add = par[256 + ch], al = alpha[ch], b2 = bias2[ch];
  int bimg = m / 49;
  int hw0 = (m - bimg * 49) * 64;
  size_t base = ((size_t)bimg * 256 + ch) * HWP + hw0 + l4 * 4;
#pragma unroll
  for (int msub = 0; msub < 4; ++msub) {
    f32x4 xv = *(const f32x4*)(x + base + msub * 16);
    f32x4 o;
#pragma unroll
    for (int r = 0; r < 4; ++r) {
      float t = fmaf(s[msub][r], mul, add) + xv[r];
      t = (t >= 0.0f) ? t : al * t;
      o[r] = t + b2;
    }
    *(f32x4*)(out + base + msub * 16) = o;
  }
}

extern "C" void kernel_launch(void* const* d_in, const int* in_sizes, int n_in,
                              void* d_out, int out_size, void* d_ws,
                              size_t ws_size, hipStream_t stream) {
  const float* x     = (const float*)d_in[0];
  const float* bias0 = (const float*)d_in[1];
  const float* w1    = (const float*)d_in[2];
  const float* w2    = (const float*)d_in[3];
  const float* w3    = (const float*)d_in[4];
  const float* gamma = (const float*)d_in[5];
  const float* beta  = (const float*)d_in[6];
  const float* bias1 = (const float*)d_in[7];
  const float* alpha = (const float*)d_in[8];
  const float* bias2 = (const float*)d_in[9];
  float* out = (float*)d_out;

  char* ws = (char*)d_ws;
  i32x4* act16     = (i32x4*)(ws + ACT_OFF);
  signed char* w8  = (signed char*)(ws + W8_OFF);
  float* scales    = (float*)(ws + SC_OFF);
  float* ps        = (float*)(ws + PS_OFF);
  float* pq        = (float*)(ws + PQ_OFF);
  float* par       = (float*)(ws + PAR_OFF);

  hipLaunchKernelGGL(k_pack_w, dim3(768), dim3(64), 0, stream, w1, w2, w3, w8,
                     scales);
  hipLaunchKernelGGL(k_pack_a, dim3(392), dim3(256), 0, stream, x, bias0,
                     act16);
  hipLaunchKernelGGL(k_stats2, dim3(NMBLK, 2), dim3(512), 0, stream, act16,
                     w8, scales, ps, pq);
  hipLaunchKernelGGL(k_bn, dim3(256), dim3(256), 0, stream, ps, pq, gamma,
                     beta, bias1, par);
  hipLaunchKernelGGL(k_out2, dim3(NMBLK, 2), dim3(512), 0, stream, act16, w8,
                     scales, par, alpha, bias2, x, out);
}

// Round 6
// 333.335 us; speedup vs baseline: 1.2567x; 1.0784x over previous
//
#include <hip/hip_runtime.h>

typedef unsigned int u32;
typedef int i32x4 __attribute__((ext_vector_type(4)));
typedef float f32x4 __attribute__((ext_vector_type(4)));

#define HWP  3136      // H*W
#define NPOS 100352    // B*H*W
#define NMBLK 1568     // NPOS / 64  (m-tiles; 49 per image)
#define MIT  4         // m-tiles per strip
#define NSTRIP 392     // NMBLK / MIT

// ---- workspace layout (bytes) ----
// act_t: chunk-major packed activations: act_t[chunk(0..15)][pos][16B]
#define ACT_OFF 0ull
#define ACT_BYTES (25690112ull)
#define W8_OFF  (ACT_OFF + ACT_BYTES)           // i8 w   [3][256][256]
#define W8_BYTES (196608ull)
#define SC_OFF  (W8_OFF + W8_BYTES)             // f32 scales [3][256]
#define SC_BYTES (3072ull)
#define PS_OFF  (SC_OFF + SC_BYTES)             // f32 ps [256][NSTRIP]
#define PS_BYTES (256ull * NSTRIP * 4)
#define PQ_OFF  (PS_OFF + PS_BYTES)             // f32 pq [256][NSTRIP]
#define PQ_BYTES (256ull * NSTRIP * 4)
#define PAR_OFF (PQ_OFF + PQ_BYTES)             // f32 par [2][256]

// K0: weights -> i8 sign (+1/-1), per-out-channel scale = mean|w|.
__global__ __launch_bounds__(64) void k_pack_w(
    const float* __restrict__ w1, const float* __restrict__ w2,
    const float* __restrict__ w3, signed char* __restrict__ w8,
    float* __restrict__ scales) {
  int bid = blockIdx.x;
  int conv = bid >> 8, p = bid & 255;
  const float* w = (conv == 0) ? w1 : (conv == 1) ? w2 : w3;
  int lane = threadIdx.x;
  float asum = 0.0f;
#pragma unroll
  for (int k = 0; k < 4; ++k) {
    float v = w[p * 256 + k * 64 + lane];
    asum += fabsf(v);
    w8[(size_t)(conv * 256 + p) * 256 + k * 64 + lane] =
        (v > 0.0f) ? (signed char)1 : (signed char)-1;
  }
#pragma unroll
  for (int off = 32; off > 0; off >>= 1) asum += __shfl_down(asum, off);
  if (lane == 0) scales[conv * 256 + p] = asum * (1.0f / 256.0f);
}

// K1: act_t[chunk][pos] = sign(x + bias0) as i8 (+1 -> 0x01, -1 -> 0xFF).
__global__ __launch_bounds__(256) void k_pack_a(
    const float* __restrict__ x, const float* __restrict__ bias0,
    i32x4* __restrict__ act16) {
  int pos = blockIdx.x * 256 + threadIdx.x;
  int b = pos / HWP;
  int hw = pos - b * HWP;
  const float* xp = x + (size_t)b * 256 * HWP + hw;
#pragma unroll 2
  for (int c16 = 0; c16 < 16; ++c16) {
    i32x4 vv;
#pragma unroll
    for (int q = 0; q < 4; ++q) {
      u32 bb = 0;
#pragma unroll
      for (int cc = 0; cc < 4; ++cc) {
        int c = c16 * 16 + q * 4 + cc;
        float v = xp[(size_t)c * HWP] + bias0[c];
        bb |= (u32)((v > 0.0f) ? 0x01u : 0xFFu) << (cc * 8);
      }
      vv[q] = (int)bb;
    }
    act16[(size_t)c16 * NPOS + pos] = vv;
  }
}

// Neighbor positions for the 9 shift variants (circular roll per image).
__device__ __forceinline__ void neighbor_pos(int row, int base, int (&p9)[9]) {
  int h = row / 56;
  int w = row - h * 56;
  p9[0] = base + row;
  int hm1 = (h == 0) ? 55 : h - 1, hp1 = (h == 55) ? 0 : h + 1;
  int wm1 = (w == 0) ? 55 : w - 1, wp1 = (w == 55) ? 0 : w + 1;
  int hm3 = (h < 3) ? h + 53 : h - 3, hp3 = (h >= 53) ? h - 53 : h + 3;
  int wm3 = (w < 3) ? w + 53 : w - 3, wp3 = (w >= 53) ? w - 53 : w + 3;
  p9[1] = base + hm1 * 56 + w;  p9[2] = base + hp1 * 56 + w;
  p9[3] = base + h * 56 + wm1;  p9[4] = base + h * 56 + wp1;
  p9[5] = base + hm3 * 56 + w;  p9[6] = base + hp3 * 56 + w;
  p9[7] = base + h * 56 + wm3;  p9[8] = base + h * 56 + wp3;
}

// Issue the 12 A-fragment loads (3 conv variants x 4 ksteps) for one msub.
// rowin = row within image; l4 selects the chunk sub-plane.
__device__ __forceinline__ void lda(const i32x4* __restrict__ act16, int base,
                                    int rowin, int l4, i32x4 (&A)[12]) {
  int p9[9];
  neighbor_pos(rowin, base, p9);
#pragma unroll
  for (int ks = 0; ks < 4; ++ks) {
    const i32x4* cb = act16 + (size_t)(ks * 4 + l4) * NPOS;
    A[ks] = cb[p9[0]];
    A[4 + ks] = cb[p9[1 + ks]];
    A[8 + ks] = cb[p9[5 + ks]];
  }
}

// 12 MFMA on one msub's A buffer -> scaled f32x4 s.
__device__ __forceinline__ f32x4 domfma(const i32x4 (&A)[12],
                                        const i32x4 (&bf)[12], float sc0,
                                        float sc1, float sc2) {
  i32x4 acc0 = {0, 0, 0, 0}, acc1 = {0, 0, 0, 0}, acc2 = {0, 0, 0, 0};
  __builtin_amdgcn_s_setprio(1);
#pragma unroll
  for (int ks = 0; ks < 4; ++ks) {
    acc0 = __builtin_amdgcn_mfma_i32_16x16x64_i8(A[ks], bf[ks], acc0, 0, 0, 0);
    acc1 = __builtin_amdgcn_mfma_i32_16x16x64_i8(A[4 + ks], bf[4 + ks], acc1, 0, 0, 0);
    acc2 = __builtin_amdgcn_mfma_i32_16x16x64_i8(A[8 + ks], bf[8 + ks], acc2, 0, 0, 0);
  }
  __builtin_amdgcn_s_setprio(0);
  f32x4 s;
#pragma unroll
  for (int r = 0; r < 4; ++r)
    s[r] = sc0 * (float)acc0[r] + sc1 * (float)acc1[r] + sc2 * (float)acc2[r];
  return s;
}

// Bijective XCD swizzle for strips (392 = 8 * 49).
__device__ __forceinline__ int swz_strip(int bid) {
  return (bid & 7) * 49 + (bid >> 3);
}

// K2: GEMM + BN-statistics partials. Block = 256 thr (4 waves x 16 ch),
// strip of MIT m-tiles. Persistent bfrag, double-buffered A pipeline.
__global__ __launch_bounds__(256, 2) void k_stats2(
    const i32x4* __restrict__ act16, const signed char* __restrict__ w8,
    const float* __restrict__ scales, float* __restrict__ ps,
    float* __restrict__ pq) {
  const int tid = threadIdx.x;
  const int lane = tid & 63, wid = tid >> 6;
  const int l15 = lane & 15, l4 = lane >> 4;
  const int ch = blockIdx.y * 64 + wid * 16 + l15;
  const int strip = swz_strip(blockIdx.x);

  i32x4 bf[3][4];
#pragma unroll
  for (int conv = 0; conv < 3; ++conv)
#pragma unroll
    for (int ks = 0; ks < 4; ++ks)
      bf[conv][ks] = *(const i32x4*)(w8 + (size_t)(conv * 256 + ch) * 256 +
                                     ks * 64 + l4 * 16);
  i32x4 bfl[12];
#pragma unroll
  for (int c = 0; c < 3; ++c)
#pragma unroll
    for (int k = 0; k < 4; ++k) bfl[c * 4 + k] = bf[c][k];
  float sc0 = scales[ch], sc1 = scales[256 + ch], sc2 = scales[512 + ch];

  i32x4 bufA[12], bufB[12];
  {
    int mt0 = strip * MIT;
    int bimg = mt0 / 49;
    int hw0 = (mt0 - bimg * 49) * 64;
    lda(act16, bimg * HWP, hw0 + l15, l4, bufA);
  }
  float ss = 0.0f, sq = 0.0f;
  for (int it = 0; it < MIT; ++it) {
    int mt = strip * MIT + it;
    int bimg = mt / 49;
    int hw0 = (mt - bimg * 49) * 64;
    int base = bimg * HWP;
#pragma unroll
    for (int msub = 0; msub < 4; ++msub) {
      i32x4(&cur)[12] = (msub & 1) ? bufB : bufA;
      i32x4(&nxt)[12] = (msub & 1) ? bufA : bufB;
      if (msub < 3) {
        lda(act16, base, hw0 + (msub + 1) * 16 + l15, l4, nxt);
      } else if (it + 1 < MIT) {
        int nmt = mt + 1;
        int nbimg = nmt / 49;
        int nhw0 = (nmt - nbimg * 49) * 64;
        lda(act16, nbimg * HWP, nhw0 + l15, l4, nxt);
      }
      f32x4 s = domfma(cur, bfl, sc0, sc1, sc2);
#pragma unroll
      for (int r = 0; r < 4; ++r) {
        ss += s[r];
        sq = fmaf(s[r], s[r], sq);
      }
    }
  }
  ss += __shfl_xor(ss, 16); sq += __shfl_xor(sq, 16);
  ss += __shfl_xor(ss, 32); sq += __shfl_xor(sq, 32);
  if (l4 == 0) {
    ps[(size_t)ch * NSTRIP + strip] = ss;
    pq[(size_t)ch * NSTRIP + strip] = sq;
  }
}

// K3: reduce partials (f64) -> folded BN affine.
__global__ __launch_bounds__(256) void k_bn(
    const float* __restrict__ ps, const float* __restrict__ pq,
    const float* __restrict__ gamma, const float* __restrict__ beta,
    const float* __restrict__ bias1, float* __restrict__ par) {
  int ch = blockIdx.x;
  int tid = threadIdx.x;
  double as = 0.0, aq = 0.0;
  for (int i = tid; i < NSTRIP; i += 256) {
    as += (double)ps[(size_t)ch * NSTRIP + i];
    aq += (double)pq[(size_t)ch * NSTRIP + i];
  }
  __shared__ double sd0[256], sd1[256];
  sd0[tid] = as; sd1[tid] = aq;
  __syncthreads();
  for (int s = 128; s > 0; s >>= 1) {
    if (tid < s) { sd0[tid] += sd0[tid + s]; sd1[tid] += sd1[tid + s]; }
    __syncthreads();
  }
  if (tid == 0) {
    double mean = sd0[0] * (1.0 / NPOS);
    double var = sd1[0] * (1.0 / NPOS) - mean * mean;
    float mm = (float)((double)gamma[ch] / sqrt(var + 1e-5));
    par[ch] = mm;
    par[256 + ch] = beta[ch] + bias1[ch] - (float)mean * mm;
  }
}

// K4: GEMM + BN affine + residual + PReLU + bias2 -> out (NCHW f32).
__global__ __launch_bounds__(256, 2) void k_out2(
    const i32x4* __restrict__ act16, const signed char* __restrict__ w8,
    const float* __restrict__ scales, const float* __restrict__ par,
    const float* __restrict__ alpha, const float* __restrict__ bias2,
    const float* __restrict__ x, float* __restrict__ out) {
  const int tid = threadIdx.x;
  const int lane = tid & 63, wid = tid >> 6;
  const int l15 = lane & 15, l4 = lane >> 4;
  const int ch = blockIdx.y * 64 + wid * 16 + l15;
  const int strip = swz_strip(blockIdx.x);

  i32x4 bf[3][4];
#pragma unroll
  for (int conv = 0; conv < 3; ++conv)
#pragma unroll
    for (int ks = 0; ks < 4; ++ks)
      bf[conv][ks] = *(const i32x4*)(w8 + (size_t)(conv * 256 + ch) * 256 +
                                     ks * 64 + l4 * 16);
  i32x4 bfl[12];
#pragma unroll
  for (int c = 0; c < 3; ++c)
#pragma unroll
    for (int k = 0; k < 4; ++k) bfl[c * 4 + k] = bf[c][k];
  float sc0 = scales[ch], sc1 = scales[256 + ch], sc2 = scales[512 + ch];
  float mul = par[ch], add = par[256 + ch], al = alpha[ch], b2 = bias2[ch];

  i32x4 bufA[12], bufB[12];
  {
    int mt0 = strip * MIT;
    int bimg = mt0 / 49;
    int hw0 = (mt0 - bimg * 49) * 64;
    lda(act16, bimg * HWP, hw0 + l15, l4, bufA);
  }
  for (int it = 0; it < MIT; ++it) {
    int mt = strip * MIT + it;
    int bimg = mt / 49;
    int hw0 = (mt - bimg * 49) * 64;
    int base = bimg * HWP;
    size_t xbase = ((size_t)bimg * 256 + ch) * HWP + hw0 + l4 * 4;
#pragma unroll
    for (int msub = 0; msub < 4; ++msub) {
      i32x4(&cur)[12] = (msub & 1) ? bufB : bufA;
      i32x4(&nxt)[12] = (msub & 1) ? bufA : bufB;
      if (msub < 3) {
        lda(act16, base, hw0 + (msub + 1) * 16 + l15, l4, nxt);
      } else if (it + 1 < MIT) {
        int nmt = mt + 1;
        int nbimg = nmt / 49;
        int nhw0 = (nmt - nbimg * 49) * 64;
        lda(act16, nbimg * HWP, nhw0 + l15, l4, nxt);
      }
      f32x4 xv = *(const f32x4*)(x + xbase + msub * 16);
      f32x4 s = domfma(cur, bfl, sc0, sc1, sc2);
      f32x4 o;
#pragma unroll
      for (int r = 0; r < 4; ++r) {
        float t = fmaf(s[r], mul, add) + xv[r];
        t = (t >= 0.0f) ? t : al * t;
        o[r] = t + b2;
      }
      *(f32x4*)(out + xbase + msub * 16) = o;
    }
  }
}

extern "C" void kernel_launch(void* const* d_in, const int* in_sizes, int n_in,
                              void* d_out, int out_size, void* d_ws,
                              size_t ws_size, hipStream_t stream) {
  const float* x     = (const float*)d_in[0];
  const float* bias0 = (const float*)d_in[1];
  const float* w1    = (const float*)d_in[2];
  const float* w2    = (const float*)d_in[3];
  const float* w3    = (const float*)d_in[4];
  const float* gamma = (const float*)d_in[5];
  const float* beta  = (const float*)d_in[6];
  const float* bias1 = (const float*)d_in[7];
  const float* alpha = (const float*)d_in[8];
  const float* bias2 = (const float*)d_in[9];
  float* out = (float*)d_out;

  char* ws = (char*)d_ws;
  i32x4* act16     = (i32x4*)(ws + ACT_OFF);
  signed char* w8  = (signed char*)(ws + W8_OFF);
  float* scales    = (float*)(ws + SC_OFF);
  float* ps        = (float*)(ws + PS_OFF);
  float* pq        = (float*)(ws + PQ_OFF);
  float* par       = (float*)(ws + PAR_OFF);

  hipLaunchKernelGGL(k_pack_w, dim3(768), dim3(64), 0, stream, w1, w2, w3, w8,
                     scales);
  hipLaunchKernelGGL(k_pack_a, dim3(392), dim3(256), 0, stream, x, bias0,
                     act16);
  hipLaunchKernelGGL(k_stats2, dim3(NSTRIP, 4), dim3(256), 0, stream, act16,
                     w8, scales, ps, pq);
  hipLaunchKernelGGL(k_bn, dim3(256), dim3(256), 0, stream, ps, pq, gamma,
                     beta, bias1, par);
  hipLaunchKernelGGL(k_out2, dim3(NSTRIP, 4), dim3(256), 0, stream, act16, w8,
                     scales, par, alpha, bias2, x, out);
}